// Round 2
// baseline (197.633 us; speedup 1.0000x reference)
//
#include <hip/hip_runtime.h>

#pragma clang fp contract(off)

typedef __attribute__((ext_vector_type(8))) short short8;
typedef __attribute__((ext_vector_type(4))) float f32x4;

#define MARGIN 0.02f

static __device__ __forceinline__ unsigned short f2b(float f) {
    union { float f; unsigned u; } x; x.f = f;
    unsigned u = x.u;
    return (unsigned short)((u + 0x7FFFu + ((u >> 16) & 1u)) >> 16);
}

// Bit-exact np distance: dot = single-accumulator ascending-k FMA chain
// on FULL-PRECISION fp32 z from global; d = (zn - 2*dot) + en.
// ES = element stride of the codebook column (1 for Et, 1024 for E).
template <int ES>
static __device__ __forceinline__ float np_dist(
    const float* __restrict__ zr, const float* __restrict__ ecol,
    float zn, float en) {
    float c = 0.f;
    #pragma unroll
    for (int i = 0; i < 64; ++i) c = fmaf(zr[i], ecol[i * ES], c);
    float t = zn - 2.f * c;
    return t + en;
}

// ---------------------------------------------------------------------------
// Merged prep (grid 16 x 256): LDS-tiled, fully coalesced.
//  - sT[64][65]: 64 rows x 64 cols of E (coalesced row reads, padded LDS)
//  - Et[k*64+d]: fp32 transpose for exact re-eval + gather           [if ET]
//  - Eb: bf16 codebook in EXACT per-lane MFMA B-fragment layout:
//      u16 element (c*1024 + s*512 + l*8 + j) = bf16(E[d][col]),
//      d = s*32 + (l>>4)*8 + j, col = c*16 + (l&15)
//    so vq_main lane l reads tile c, half s as one contiguous 16B load. [if EB]
//  - enorm[k]: ascending-d fmaf chain (np axis-0 reduce order)
//  - zero loss + completion counter
// ---------------------------------------------------------------------------
template <bool ET, bool EB>
__global__ __launch_bounds__(256) void vq_prep_all(
    const float* __restrict__ E, float* __restrict__ ws_loss,
    unsigned* __restrict__ ws_cnt, float* __restrict__ enorm,
    float* __restrict__ Et, unsigned* __restrict__ EbW) {
    __shared__ float sT[64][65];
    const int tid = threadIdx.x;
    const int w = tid >> 6;
    const int m64 = tid & 63;
    const int c0 = blockIdx.x * 64;

    #pragma unroll
    for (int r = 0; r < 16; ++r) {
        const int row = r * 4 + w;
        sT[row][m64] = E[row * 1024 + c0 + m64];
    }
    __syncthreads();

    if (ET) {
        #pragma unroll
        for (int it = 0; it < 16; ++it) {
            const int e = it * 256 + tid;   // 0..4095
            const int col = e >> 6, d = e & 63;
            Et[(c0 + col) * 64 + d] = sT[d][col];
        }
    }
    if (EB) {
        #pragma unroll
        for (int it = 0; it < 8; ++it) {
            const int w0 = it * 256 + tid;  // 0..2047 (u32 words)
            const int cl = w0 >> 9;         // local 16-col tile 0..3
            const int s = (w0 >> 8) & 1;
            const int l = (w0 >> 2) & 63;
            const int j = (w0 & 3) * 2;
            const int d = s * 32 + (l >> 4) * 8 + j;
            const int col = cl * 16 + (l & 15);
            const unsigned lo = f2b(sT[d][col]);
            const unsigned hi = f2b(sT[d + 1][col]);
            EbW[(blockIdx.x * 4 + cl) * 512 + (w0 & 511)] = lo | (hi << 16);
        }
    }
    if (tid < 64) {
        float s2 = 0.f;
        #pragma unroll
        for (int d = 0; d < 64; ++d) {
            float v = sT[d][tid];
            s2 = fmaf(v, v, s2);
        }
        enorm[c0 + tid] = s2;
    }
    if (blockIdx.x == 0 && tid == 0) { *ws_loss = 0.f; *ws_cnt = 0u; }
}

// ---------------------------------------------------------------------------
// Main kernel: NO LDS staging of B — fragments read directly from the
// precomputed fragment-layout Eb (128 KB, L2-resident) as coalesced 16B
// per-lane loads. No barriers in the screening loop -> waves independent.
// Packed top-2 (tile idx in low 6 mantissa bits, << MARGIN) via med3+min.
// Exact fp32 re-eval + gather + loss unchanged (bit-exact np semantics).
// Loss finalization folded in: last block to finish writes the scalar.
// Block = 256 (4 waves), 128 rows, grid = 1024. LDS ~5.2 KB.
// ---------------------------------------------------------------------------
template <bool USE_ET, bool USE_EB>
__global__ __launch_bounds__(256) void vq_main(
    const float* __restrict__ z, const float* __restrict__ E,
    const float* __restrict__ Et, const unsigned short* __restrict__ Eb,
    const float* __restrict__ enorm,
    float* __restrict__ ws_loss, unsigned* __restrict__ ws_cnt,
    float* __restrict__ out) {
    __shared__ unsigned short sB[USE_EB ? 64 : 128 * 64];
    __shared__ float sEn[1024];
    __shared__ float sZn[128];
    __shared__ int sIdx[128];
    __shared__ float sRed[4];

    const int tid = threadIdx.x;
    const int w = tid >> 6;
    const int l = tid & 63;
    const int quad = l >> 4;
    const int m = l & 15;
    const int b = blockIdx.x;

    ((float4*)sEn)[tid] = ((const float4*)enorm)[tid];

    // znorm: bit-exact numpy pairwise sum (SSE path, 4 accumulators, hadd).
    if (tid < 128) {
        const float* zr = z + (b * 128 + tid) * 64;
        float S[16];
        #pragma unroll
        for (int u = 0; u < 16; ++u) { float v = zr[u]; S[u] = v * v; }
        #pragma unroll
        for (int t = 1; t < 4; ++t)
            #pragma unroll
            for (int u = 0; u < 16; ++u) {
                float v = zr[16 * t + u];
                float sq = v * v;
                S[u] = S[u] + sq;
            }
        float R0 = (S[0] + S[4]) + (S[8] + S[12]);
        float R1 = (S[1] + S[5]) + (S[9] + S[13]);
        float R2 = (S[2] + S[6]) + (S[10] + S[14]);
        float R3 = (S[3] + S[7]) + (S[11] + S[15]);
        sZn[tid] = (R0 + R1) + (R2 + R3);
    }

    // A fragments (fp32 -> bf16 RNE for the screening MFMA)
    short8 a[2][2];
    #pragma unroll
    for (int rt = 0; rt < 2; ++rt) {
        const int rowl = w * 32 + rt * 16 + m;
        #pragma unroll
        for (int s = 0; s < 2; ++s) {
            const float* zp = z + (b * 128 + rowl) * 64 + s * 32 + quad * 8;
            union { float4 v; float f[4]; } u0, u1;
            u0.v = *(const float4*)zp;
            u1.v = *(const float4*)(zp + 4);
            short8 av;
            #pragma unroll
            for (int j = 0; j < 4; ++j) av[j] = (short)f2b(u0.f[j]);
            #pragma unroll
            for (int j = 0; j < 4; ++j) av[4 + j] = (short)f2b(u1.f[j]);
            a[rt][s] = av;
        }
    }

    // packed top-2 per lane-slot: value with 16-col tile index c in low 6 bits
    float v1p[2][4], v2p[2][4];
    #pragma unroll
    for (int rt = 0; rt < 2; ++rt)
        #pragma unroll
        for (int r = 0; r < 4; ++r) { v1p[rt][r] = 3.4e38f; v2p[rt][r] = 3.4e38f; }

    if constexpr (USE_EB) {
        __syncthreads();  // sEn (and sZn) ready; only barrier before re-eval
        const unsigned short* __restrict__ ebp = Eb + l * 8;
        #pragma unroll 8
        for (int c = 0; c < 64; ++c) {
            short8 b0 = *(const short8*)(ebp + c * 1024);
            short8 b1 = *(const short8*)(ebp + c * 1024 + 512);
            f32x4 acc0 = {0.f, 0.f, 0.f, 0.f};
            f32x4 acc1 = {0.f, 0.f, 0.f, 0.f};
            acc0 = __builtin_amdgcn_mfma_f32_16x16x32_bf16(a[0][0], b0, acc0, 0, 0, 0);
            acc0 = __builtin_amdgcn_mfma_f32_16x16x32_bf16(a[0][1], b1, acc0, 0, 0, 0);
            acc1 = __builtin_amdgcn_mfma_f32_16x16x32_bf16(a[1][0], b0, acc1, 0, 0, 0);
            acc1 = __builtin_amdgcn_mfma_f32_16x16x32_bf16(a[1][1], b1, acc1, 0, 0, 0);
            const float en = sEn[c * 16 + m];
            #pragma unroll
            for (int r = 0; r < 4; ++r) {
                float p0 = fmaf(-2.f, acc0[r], en);
                p0 = __uint_as_float((__float_as_uint(p0) & 0xFFFFFFC0u) | (unsigned)c);
                v2p[0][r] = __builtin_amdgcn_fmed3f(p0, v1p[0][r], v2p[0][r]);
                v1p[0][r] = fminf(p0, v1p[0][r]);
                float p1 = fmaf(-2.f, acc1[r], en);
                p1 = __uint_as_float((__float_as_uint(p1) & 0xFFFFFFC0u) | (unsigned)c);
                v2p[1][r] = __builtin_amdgcn_fmed3f(p1, v1p[1][r], v2p[1][r]);
                v1p[1][r] = fminf(p1, v1p[1][r]);
            }
        }
    } else {
        // fallback: in-kernel fp32->bf16 conversion + LDS swizzle staging
        for (int st = 0; st < 8; ++st) {
            #pragma unroll
            for (int i = 0; i < 4; ++i) {
                const int u = tid + i * 256;
                const int d0 = (u & 31) * 2;
                const int cg = u >> 5;
                const float* e0 = E + d0 * 1024 + st * 128 + cg * 4;
                union { float4 v; float f[4]; } va, vb;
                va.v = *(const float4*)e0;
                vb.v = *(const float4*)(e0 + 1024);
                #pragma unroll
                for (int j = 0; j < 4; ++j) {
                    const int col = cg * 4 + j;
                    const unsigned lo = f2b(va.f[j]);
                    const unsigned hi = f2b(vb.f[j]);
                    const int gi = col * 8 + ((d0 >> 3) ^ (col & 7));
                    *(unsigned*)&sB[gi * 8 + (d0 & 7)] = lo | (hi << 16);
                }
            }
            __syncthreads();
            #pragma unroll
            for (int ct = 0; ct < 8; ++ct) {
                const int c = st * 8 + ct;
                const int colb = (ct * 16 + m) * 8;
                short8 b0 = *(const short8*)&sB[(colb + (quad ^ (m & 7))) * 8];
                short8 b1 = *(const short8*)&sB[(colb + ((4 + quad) ^ (m & 7))) * 8];
                f32x4 acc0 = {0.f, 0.f, 0.f, 0.f};
                f32x4 acc1 = {0.f, 0.f, 0.f, 0.f};
                acc0 = __builtin_amdgcn_mfma_f32_16x16x32_bf16(a[0][0], b0, acc0, 0, 0, 0);
                acc0 = __builtin_amdgcn_mfma_f32_16x16x32_bf16(a[0][1], b1, acc0, 0, 0, 0);
                acc1 = __builtin_amdgcn_mfma_f32_16x16x32_bf16(a[1][0], b0, acc1, 0, 0, 0);
                acc1 = __builtin_amdgcn_mfma_f32_16x16x32_bf16(a[1][1], b1, acc1, 0, 0, 0);
                const float en = sEn[c * 16 + m];
                #pragma unroll
                for (int r = 0; r < 4; ++r) {
                    float p0 = fmaf(-2.f, acc0[r], en);
                    p0 = __uint_as_float((__float_as_uint(p0) & 0xFFFFFFC0u) | (unsigned)c);
                    v2p[0][r] = __builtin_amdgcn_fmed3f(p0, v1p[0][r], v2p[0][r]);
                    v1p[0][r] = fminf(p0, v1p[0][r]);
                    float p1 = fmaf(-2.f, acc1[r], en);
                    p1 = __uint_as_float((__float_as_uint(p1) & 0xFFFFFFC0u) | (unsigned)c);
                    v2p[1][r] = __builtin_amdgcn_fmed3f(p1, v1p[1][r], v2p[1][r]);
                    v1p[1][r] = fminf(p1, v1p[1][r]);
                }
            }
            __syncthreads();
        }
    }

    // exact re-evaluation (fp32 z from global, E column from Et/E);
    // lexicographic (d, k) min = np first-occurrence tie-break
    float la = 0.f;
    #pragma unroll
    for (int rt = 0; rt < 2; ++rt) {
        #pragma unroll
        for (int r = 0; r < 4; ++r) {
            float pv1 = v1p[rt][r];
            float vb = pv1;
            #pragma unroll
            for (int mask = 1; mask <= 8; mask <<= 1)
                vb = fminf(vb, __shfl_xor(vb, mask));
            const int rowl = w * 32 + rt * 16 + quad * 4 + r;
            const float zn = sZn[rowl];
            const float* zr = z + (b * 128 + rowl) * 64;
            float d = 3.4e38f;
            int kk = 0x7fffffff;
            if (pv1 <= vb + MARGIN) {
                kk = (int)(__float_as_uint(pv1) & 63u) * 16 + m;
                d = USE_ET ? np_dist<1>(zr, Et + kk * 64, zn, sEn[kk])
                           : np_dist<1024>(zr, E + kk, zn, sEn[kk]);
            }
            float pv2 = v2p[rt][r];
            if (pv2 <= vb + MARGIN) {
                int kc = (int)(__float_as_uint(pv2) & 63u) * 16 + m;
                float dd = USE_ET ? np_dist<1>(zr, Et + kc * 64, zn, sEn[kc])
                                  : np_dist<1024>(zr, E + kc, zn, sEn[kc]);
                if (dd < d || (dd == d && kc < kk)) { d = dd; kk = kc; }
            }
            #pragma unroll
            for (int mask = 1; mask <= 8; mask <<= 1) {
                float d2 = __shfl_xor(d, mask);
                int c2 = __shfl_xor(kk, mask);
                bool take = (d2 < d) || (d2 == d && c2 < kk);
                d = take ? d2 : d;
                kk = take ? c2 : kk;
            }
            if (m == 0) {
                sIdx[rowl] = kk;
                la += d;
            }
        }
    }
    __syncthreads();

    // gather: 2 lanes/row, 32 dims each (contiguous from Et when available)
    {
        const int row_local = w * 32 + (l >> 1);
        const int half = l & 1;
        const int idx = sIdx[row_local];
        union { float s[32]; float4 f[8]; } tmp;
        if (USE_ET) {
            const float4* src = (const float4*)(Et + idx * 64 + half * 32);
            #pragma unroll
            for (int q4 = 0; q4 < 8; ++q4) tmp.f[q4] = src[q4];
        } else {
            #pragma unroll
            for (int dd = 0; dd < 32; ++dd) tmp.s[dd] = E[(half * 32 + dd) * 1024 + idx];
        }
        float4* dst = (float4*)(out + (b * 128 + row_local) * 64 + half * 32);
        #pragma unroll
        for (int q4 = 0; q4 < 8; ++q4) dst[q4] = tmp.f[q4];
    }

    #pragma unroll
    for (int mask = 32; mask >= 1; mask >>= 1) la += __shfl_xor(la, mask);
    if (l == 0) sRed[w] = la;
    __syncthreads();

    // loss accumulate; last block to finish writes the final scalar
    if (tid == 0) {
        atomicAdd(ws_loss, sRed[0] + sRed[1] + sRed[2] + sRed[3]);
        __threadfence();
        const unsigned done = atomicAdd(ws_cnt, 1u);
        if (done == 1023u) {
            const float total = atomicAdd(ws_loss, 0.f);  // device-scope read
            out[8388608] = total * (1.25f / 8388608.f);
        }
    }
}

extern "C" void kernel_launch(void* const* d_in, const int* in_sizes, int n_in,
                              void* d_out, int out_size, void* d_ws, size_t ws_size,
                              hipStream_t stream) {
    const float* z = (const float*)d_in[0];  // fp32 [131072,64]
    const float* E = (const float*)d_in[1];  // fp32 [64,1024]
    float* out = (float*)d_out;              // fp32 [8388609]

    char* ws = (char*)d_ws;
    float* loss = (float*)ws;                          // 4 B
    unsigned* cnt = (unsigned*)(ws + 4);               // 4 B
    float* enorm = (float*)(ws + 128);                 // 4 KB
    unsigned short* Eb = (unsigned short*)(ws + 8192); // 128 KB fragment-layout bf16
    float* Et = (float*)(ws + 139264);                 // 256 KB fp32 transpose
    const bool useEb = ws_size >= (size_t)139264;
    const bool useEt = ws_size >= (size_t)401408;

    if (useEt) {
        vq_prep_all<true, true><<<16, 256, 0, stream>>>(E, loss, cnt, enorm, Et, (unsigned*)Eb);
        vq_main<true, true><<<1024, 256, 0, stream>>>(z, E, Et, Eb, enorm, loss, cnt, out);
    } else if (useEb) {
        vq_prep_all<false, true><<<16, 256, 0, stream>>>(E, loss, cnt, enorm, Et, (unsigned*)Eb);
        vq_main<false, true><<<1024, 256, 0, stream>>>(z, E, Et, Eb, enorm, loss, cnt, out);
    } else {
        vq_prep_all<false, false><<<16, 256, 0, stream>>>(E, loss, cnt, enorm, Et, (unsigned*)Eb);
        vq_main<false, false><<<1024, 256, 0, stream>>>(z, E, Et, Eb, enorm, loss, cnt, out);
    }
}